// Round 9
// baseline (249.240 us; speedup 1.0000x reference)
//
#include <hip/hip_runtime.h>
#include <math.h>

#define N_PTS  1000000
#define M_COMP 64

typedef float v2f __attribute__((ext_vector_type(2)));

__device__ __forceinline__ float exp2n(float x) { return __builtin_amdgcn_exp2f(x); }
__device__ __forceinline__ float log2n(float x) { return __builtin_amdgcn_logf(x); }

// ---------------------------------------------------------------------------
// DIAGNOSTIC ROUND (ablation, m164/m165 style). Four tall variants of the
// exact R4 17.8us structure, REPS internal repetitions each so they exceed
// the harness's ~39us fill dispatches and surface in rocprof top-5 with
// readable VALUBusy / VGPR / FETCH / Occupancy.
//   MODE 0: FULL  — exact R4 math, writes real d_out (last rep, bit-exact)
//   MODE 1: NOEXP — acc += s      (isolates transcendental-pipe cost)
//   MODE 2: NOLDS — chunk-0 coefs in regs for all chunks (isolates LDS cost)
//   MODE 3: NOFMA — skip 5-fma chain, loads kept live    (isolates fma cost)
// Anti-CSE: opaque-touch (asm "+v") of the point values and an opaque zero
// LDS-index offset per rep, so reps can't be hoisted/merged; end-of-rep
// liveness fence (asm "v") so earlier reps aren't DCE'd (rule #17).
// ---------------------------------------------------------------------------
template<int MODE, int REPS>
__global__ __launch_bounds__(256) void gm_diag(
    const float* __restrict__ sample, // (N,2)
    const float* __restrict__ mu,     // (64,2)
    const float* __restrict__ A,      // (64,2,2)
    const float* __restrict__ w,      // (64,1)
    float* __restrict__ out)          // (N,1) or ws scratch
{
    __shared__ float cf[6 * M_COMP];

    const int tid = threadIdx.x;
    const float L2E = 1.4426950408889634f;
    const float LN2 = 0.6931471805599453f;

    if (tid < 64) {                       // wave 0: coefficient phase (R4)
        const int j = tid;
        const float a00 = A[j*4+0], a01 = A[j*4+1], a10 = A[j*4+2], a11 = A[j*4+3];
        const float g00 = 0.5f*(a00*a00 + a01*a01);
        const float g01 = 0.5f*(a00*a10 + a01*a11);
        const float g11 = 0.5f*(a10*a10 + a11*a11);
        const float det = g00*g11 - g01*g01;

        const float m0 = mu[j*2+0], m1 = mu[j*2+1];
        const float Gmu0 = g00*m0 + g01*m1;
        const float Gmu1 = g01*m0 + g11*m1;
        const float cst  = m0*Gmu0 + m1*Gmu1;

        const float wj = w[j];
        float mx = wj;
        #pragma unroll
        for (int m = 1; m < 64; m <<= 1)
            mx = fmaxf(mx, __shfl_xor(mx, m, 64));
        float se = exp2n((wj - mx) * L2E);
        #pragma unroll
        for (int m = 1; m < 64; m <<= 1)
            se += __shfl_xor(se, m, 64);
        const float lse  = mx + log2n(se) * LN2;
        const float wlog = wj - lse + 0.5f * log2n(det) * LN2;

        cf[0*M_COMP+j] = -g00 * L2E;
        cf[1*M_COMP+j] = -(g01+g01) * L2E;
        cf[2*M_COMP+j] = -g11 * L2E;
        cf[3*M_COMP+j] = (Gmu0+Gmu0) * L2E;
        cf[4*M_COMP+j] = (Gmu1+Gmu1) * L2E;
        cf[5*M_COMP+j] = (wlog - cst) * L2E;
    }
    __syncthreads();

    const int t  = blockIdx.x * 256 + tid;   // 4 points per thread
    const int p0 = t * 4;
    const bool ok = p0 < N_PTS;
    const int  pl = ok ? p0 : 0;

    const float4* s4 = (const float4*)sample;
    float4 qa = s4[(pl >> 1) + 0];           // points p0, p0+1
    float4 qb = s4[(pl >> 1) + 1];           // points p0+2, p0+3

    // MODE 2: preload chunk-0 coefficients, reused for all chunks (no ds in loop)
    float4 k0, k1, k2, k3, k4, k5;
    if constexpr (MODE == 2) {
        k0 = *(const float4*)&cf[0*M_COMP];
        k1 = *(const float4*)&cf[1*M_COMP];
        k2 = *(const float4*)&cf[2*M_COMP];
        k3 = *(const float4*)&cf[3*M_COMP];
        k4 = *(const float4*)&cf[4*M_COMP];
        k5 = *(const float4*)&cf[5*M_COMP];
    }

    v2f accA0, accA1, accB0, accB1;

    #pragma unroll 1
    for (int rep = 0; rep < REPS; ++rep) {
        // opaque-touch inputs: reps can't be CSE'd/hoisted (values unchanged)
        asm volatile("" : "+v"(qa.x), "+v"(qa.y), "+v"(qa.z), "+v"(qa.w),
                          "+v"(qb.x), "+v"(qb.y), "+v"(qb.z), "+v"(qb.w));
        int zoff = 0;                         // opaque zero: blocks LICM of the
        asm volatile("" : "+v"(zoff));        // 96 LDS loads out of the rep loop

        const v2f ax0 = {qa.x, qa.z}, ax1 = {qa.y, qa.w};
        const v2f bx0 = {qb.x, qb.z}, bx1 = {qb.y, qb.w};
        const v2f axx0 = ax0*ax0, ax01 = ax0*ax1, axx1 = ax1*ax1;
        const v2f bxx0 = bx0*bx0, bx01 = bx0*bx1, bxx1 = bx1*bx1;

        accA0 = (v2f){0.f, 0.f}; accA1 = (v2f){0.f, 0.f};
        accB0 = (v2f){0.f, 0.f}; accB1 = (v2f){0.f, 0.f};

        #pragma unroll 4
        for (int jc = 0; jc < M_COMP; jc += 4) {
            float4 c0, c1, c2, c3, c4, c5;
            if constexpr (MODE == 2) {
                c0 = k0; c1 = k1; c2 = k2; c3 = k3; c4 = k4; c5 = k5;
            } else {
                c0 = *(const float4*)&cf[0*M_COMP + jc + zoff];
                c1 = *(const float4*)&cf[1*M_COMP + jc + zoff];
                c2 = *(const float4*)&cf[2*M_COMP + jc + zoff];
                c3 = *(const float4*)&cf[3*M_COMP + jc + zoff];
                c4 = *(const float4*)&cf[4*M_COMP + jc + zoff];
                c5 = *(const float4*)&cf[5*M_COMP + jc + zoff];
            }
            if constexpr (MODE == 3) {
                // keep the full b128 loads live without using them in math
                asm volatile("" ::
                    "v"(c0.x), "v"(c0.y), "v"(c0.z), "v"(c0.w),
                    "v"(c1.x), "v"(c1.y), "v"(c1.z), "v"(c1.w),
                    "v"(c2.x), "v"(c2.y), "v"(c2.z), "v"(c2.w),
                    "v"(c3.x), "v"(c3.y), "v"(c3.z), "v"(c3.w),
                    "v"(c4.x), "v"(c4.y), "v"(c4.z), "v"(c4.w));
            }

#define GM_COMP(F, ACCA, ACCB)                                              \
            {                                                               \
                v2f s = {c5.F, c5.F};                                       \
                v2f r = {c5.F, c5.F};                                       \
                if constexpr (MODE != 3) {                                  \
                    s = __builtin_elementwise_fma(ax1,  (v2f){c4.F, c4.F}, s);\
                    s = __builtin_elementwise_fma(ax0,  (v2f){c3.F, c3.F}, s);\
                    s = __builtin_elementwise_fma(axx1, (v2f){c2.F, c2.F}, s);\
                    s = __builtin_elementwise_fma(ax01, (v2f){c1.F, c1.F}, s);\
                    s = __builtin_elementwise_fma(axx0, (v2f){c0.F, c0.F}, s);\
                    r = __builtin_elementwise_fma(bx1,  (v2f){c4.F, c4.F}, r);\
                    r = __builtin_elementwise_fma(bx0,  (v2f){c3.F, c3.F}, r);\
                    r = __builtin_elementwise_fma(bxx1, (v2f){c2.F, c2.F}, r);\
                    r = __builtin_elementwise_fma(bx01, (v2f){c1.F, c1.F}, r);\
                    r = __builtin_elementwise_fma(bxx0, (v2f){c0.F, c0.F}, r);\
                }                                                           \
                if constexpr (MODE == 1) {                                  \
                    ACCA += s;                                              \
                    ACCB += r;                                              \
                } else {                                                    \
                    ACCA[0] += exp2n(s[0]);                                 \
                    ACCA[1] += exp2n(s[1]);                                 \
                    ACCB[0] += exp2n(r[0]);                                 \
                    ACCB[1] += exp2n(r[1]);                                 \
                }                                                           \
            }
            GM_COMP(x, accA0, accB0)
            GM_COMP(y, accA1, accB1)
            GM_COMP(z, accA0, accB0)
            GM_COMP(w, accA1, accB1)
#undef GM_COMP
        }

        // liveness fence: earlier reps' results are consumed, not DCE'd
        {
            float u0 = accA0[0], u1 = accA0[1], u2 = accA1[0], u3 = accA1[1];
            float u4 = accB0[0], u5 = accB0[1], u6 = accB1[0], u7 = accB1[1];
            asm volatile("" :: "v"(u0), "v"(u1), "v"(u2), "v"(u3),
                               "v"(u4), "v"(u5), "v"(u6), "v"(u7));
        }
    }

    if (ok) {                                 // last rep == exact R4 output
        const v2f accA = accA0 + accA1;
        const v2f accB = accB0 + accB1;
        float4 o;
        o.x = log2n(accA[0]) * LN2;
        o.y = log2n(accA[1]) * LN2;
        o.z = log2n(accB[0]) * LN2;
        o.w = log2n(accB[1]) * LN2;
        *(float4*)&out[p0] = o;
    }
}

extern "C" void kernel_launch(void* const* d_in, const int* in_sizes, int n_in,
                              void* d_out, int out_size, void* d_ws, size_t ws_size,
                              hipStream_t stream)
{
    const float* sample = (const float*)d_in[0];  // (1e6, 2) f32
    const float* mu     = (const float*)d_in[1];  // (64, 2)  f32
    const float* A      = (const float*)d_in[2];  // (64,2,2) f32
    const float* w      = (const float*)d_in[3];  // (64, 1)  f32
    float* out = (float*)d_out;                   // (1e6, 1) f32
    float* wsf = (float*)d_ws;                    // 268 MB scratch

    const int blocks = (N_PTS/4 + 255) / 256;     // 977, same as R4

    // FULL writes the real output (bit-exact R4 math on the last rep).
    gm_diag<0,  8><<<blocks, 256, 0, stream>>>(sample, mu, A, w, out);
    // Ablations write to disjoint ws scratch (never validated).
    gm_diag<1, 12><<<blocks, 256, 0, stream>>>(sample, mu, A, w, wsf +  2*1024*1024);
    gm_diag<2,  8><<<blocks, 256, 0, stream>>>(sample, mu, A, w, wsf +  8*1024*1024);
    gm_diag<3,  8><<<blocks, 256, 0, stream>>>(sample, mu, A, w, wsf + 14*1024*1024);
}

// Round 10
// 17.549 us; speedup vs baseline: 14.2024x; 14.2024x over previous
//
#include <hip/hip_runtime.h>
#include <math.h>

#define N_PTS  1000000
#define M_COMP 64

typedef float v2f __attribute__((ext_vector_type(2)));

__device__ __forceinline__ float exp2n(float x) { return __builtin_amdgcn_exp2f(x); }
__device__ __forceinline__ float log2n(float x) { return __builtin_amdgcn_logf(x); }

// ---------------------------------------------------------------------------
// R9 ablation verdict: inner loop was ~30 VALU instr/comp (scalarized v2f +
// 6 splat v_movs per comp). Fix: pack 2 COMPONENTS per v2f, not 2 points.
//  - coef v2f pairs {c[j],c[j+1]} are register-adjacent halves of the float4
//    chunk loads -> zero-cost operands (no splats, no extraction)
//  - point values (x0, x1, x0^2, x0*x1, x1^2) become the splatted operand,
//    but they are comp-loop-INVARIANT -> hoisted once per thread
//  - even if still scalarized: scalar fmas share the point register directly,
//    0 movs; 12 VALU instr / 2 comps (was 24+6)
// Accumulator = v2f over comp-pairs per point; max-free logsumexp makes the
// final merge one horizontal add. Output unchanged bit-wise up to fp32
// reassociation (threshold 0.075, we sit at ~0.016).
// Structure otherwise identical to the 17.8us R4 kernel: fused, wave-0 coef
// phase -> LDS SoA cf[k][64], 4 points/thread, native v_exp_f32.
// ---------------------------------------------------------------------------
__global__ __launch_bounds__(256) void gm_fused(
    const float* __restrict__ sample, // (N,2)
    const float* __restrict__ mu,     // (64,2)
    const float* __restrict__ A,      // (64,2,2)
    const float* __restrict__ w,      // (64,1)
    float* __restrict__ out)          // (N,1)
{
    __shared__ float cf[6 * M_COMP];

    const int tid = threadIdx.x;
    const float L2E = 1.4426950408889634f;
    const float LN2 = 0.6931471805599453f;

    if (tid < 64) {                       // wave 0: coefficient phase
        const int j = tid;
        const float a00 = A[j*4+0], a01 = A[j*4+1], a10 = A[j*4+2], a11 = A[j*4+3];
        const float g00 = 0.5f*(a00*a00 + a01*a01);
        const float g01 = 0.5f*(a00*a10 + a01*a11);
        const float g11 = 0.5f*(a10*a10 + a11*a11);
        const float det = g00*g11 - g01*g01;

        const float m0 = mu[j*2+0], m1 = mu[j*2+1];
        const float Gmu0 = g00*m0 + g01*m1;
        const float Gmu1 = g01*m0 + g11*m1;
        const float cst  = m0*Gmu0 + m1*Gmu1;

        const float wj = w[j];
        float mx = wj;
        #pragma unroll
        for (int m = 1; m < 64; m <<= 1)
            mx = fmaxf(mx, __shfl_xor(mx, m, 64));
        float se = exp2n((wj - mx) * L2E);
        #pragma unroll
        for (int m = 1; m < 64; m <<= 1)
            se += __shfl_xor(se, m, 64);
        const float lse  = mx + log2n(se) * LN2;
        const float wlog = wj - lse + 0.5f * log2n(det) * LN2;

        cf[0*M_COMP+j] = -g00 * L2E;
        cf[1*M_COMP+j] = -(g01+g01) * L2E;
        cf[2*M_COMP+j] = -g11 * L2E;
        cf[3*M_COMP+j] = (Gmu0+Gmu0) * L2E;
        cf[4*M_COMP+j] = (Gmu1+Gmu1) * L2E;
        cf[5*M_COMP+j] = (wlog - cst) * L2E;
    }
    __syncthreads();

    const int t  = blockIdx.x * 256 + tid;   // 4 points per thread
    const int p0 = t * 4;
    const bool ok = p0 < N_PTS;
    const int  pl = ok ? p0 : 0;             // clamp OOB, keep wave intact

    const float4* s4 = (const float4*)sample;
    const float4 qa = s4[(pl >> 1) + 0];     // points p0, p0+1
    const float4 qb = s4[(pl >> 1) + 1];     // points p0+2, p0+3

    // Per-point values, hoisted (comp-loop-invariant). Static 4-unroll only —
    // never runtime-indexed (rule #20).
    const float x0v[4]  = {qa.x, qa.z, qb.x, qb.z};
    const float x1v[4]  = {qa.y, qa.w, qb.y, qb.w};
    float xx0v[4], x01v[4], xx1v[4];
    #pragma unroll
    for (int p = 0; p < 4; ++p) {
        xx0v[p] = x0v[p]*x0v[p];
        x01v[p] = x0v[p]*x1v[p];
        xx1v[p] = x1v[p]*x1v[p];
    }

    v2f acc[4] = {{0.f,0.f},{0.f,0.f},{0.f,0.f},{0.f,0.f}}; // [point] over comp-pair

    #pragma unroll 2
    for (int jc = 0; jc < M_COMP; jc += 4) {
        const float4 c0 = *(const float4*)&cf[0*M_COMP+jc];
        const float4 c1 = *(const float4*)&cf[1*M_COMP+jc];
        const float4 c2 = *(const float4*)&cf[2*M_COMP+jc];
        const float4 c3 = *(const float4*)&cf[3*M_COMP+jc];
        const float4 c4 = *(const float4*)&cf[4*M_COMP+jc];
        const float4 c5 = *(const float4*)&cf[5*M_COMP+jc];

        // zero-cost v2f views of the float4 halves (register-adjacent)
        const v2f c0lo = {c0.x, c0.y}, c0hi = {c0.z, c0.w};
        const v2f c1lo = {c1.x, c1.y}, c1hi = {c1.z, c1.w};
        const v2f c2lo = {c2.x, c2.y}, c2hi = {c2.z, c2.w};
        const v2f c3lo = {c3.x, c3.y}, c3hi = {c3.z, c3.w};
        const v2f c4lo = {c4.x, c4.y}, c4hi = {c4.z, c4.w};
        const v2f c5lo = {c5.x, c5.y}, c5hi = {c5.z, c5.w};

        #pragma unroll
        for (int p = 0; p < 4; ++p) {
            const v2f X0  = {x0v[p],  x0v[p]};   // hoistable splats (invariant
            const v2f X1  = {x1v[p],  x1v[p]};   // across the jc loop)
            const v2f XX0 = {xx0v[p], xx0v[p]};
            const v2f X01 = {x01v[p], x01v[p]};
            const v2f XX1 = {xx1v[p], xx1v[p]};

            v2f s = c5lo;                        // comps jc, jc+1
            s = __builtin_elementwise_fma(c4lo, X1,  s);
            s = __builtin_elementwise_fma(c3lo, X0,  s);
            s = __builtin_elementwise_fma(c2lo, XX1, s);
            s = __builtin_elementwise_fma(c1lo, X01, s);
            s = __builtin_elementwise_fma(c0lo, XX0, s);
            acc[p][0] += exp2n(s[0]);
            acc[p][1] += exp2n(s[1]);

            v2f r = c5hi;                        // comps jc+2, jc+3
            r = __builtin_elementwise_fma(c4hi, X1,  r);
            r = __builtin_elementwise_fma(c3hi, X0,  r);
            r = __builtin_elementwise_fma(c2hi, XX1, r);
            r = __builtin_elementwise_fma(c1hi, X01, r);
            r = __builtin_elementwise_fma(c0hi, XX0, r);
            acc[p][0] += exp2n(r[0]);
            acc[p][1] += exp2n(r[1]);
        }
    }

    if (ok) {
        float4 o;                                // horizontal comp-pair merge
        o.x = log2n(acc[0][0] + acc[0][1]) * LN2;
        o.y = log2n(acc[1][0] + acc[1][1]) * LN2;
        o.z = log2n(acc[2][0] + acc[2][1]) * LN2;
        o.w = log2n(acc[3][0] + acc[3][1]) * LN2;
        *(float4*)&out[p0] = o;
    }
}

extern "C" void kernel_launch(void* const* d_in, const int* in_sizes, int n_in,
                              void* d_out, int out_size, void* d_ws, size_t ws_size,
                              hipStream_t stream)
{
    const float* sample = (const float*)d_in[0];  // (1e6, 2) f32
    const float* mu     = (const float*)d_in[1];  // (64, 2)  f32
    const float* A      = (const float*)d_in[2];  // (64,2,2) f32
    const float* w      = (const float*)d_in[3];  // (64, 1)  f32
    float* out = (float*)d_out;                   // (1e6, 1) f32

    const int blocks = (N_PTS/4 + 255) / 256;     // 977
    gm_fused<<<blocks, 256, 0, stream>>>(sample, mu, A, w, out);
}